// Round 1
// baseline (391.931 us; speedup 1.0000x reference)
//
#include <hip/hip_runtime.h>

#define DIM 4096
#define K_SEL 204          // int(4096 * (1.0 - 0.95)) == 204
#define TPB 256
#define EPT (DIM / TPB)    // 16 elements per thread
#define CAND_A 1.0f        // candidate threshold: P(x>1)=.159 -> ~650 cands >> 204

// Monotonic key: ascending key order == ascending float order.
__device__ __forceinline__ unsigned int fkey(float f) {
    unsigned int u = __float_as_uint(f);
    return (u & 0x80000000u) ? ~u : (u | 0x80000000u);
}

// Wave-aggregated LDS histogram add: one atomic per distinct bucket per wave.
__device__ __forceinline__ void hist_add_wave(unsigned int* hist, int bucket,
                                              bool pred, int lane) {
    unsigned long long act = __ballot(pred);
    while (act) {
        int leader = (int)__ffsll(act) - 1;
        int lb = __shfl(bucket, leader, 64);
        unsigned long long match = __ballot(pred && (bucket == lb));
        if (lane == leader) atomicAdd(&hist[lb], (unsigned int)__popcll(match));
        act &= ~match;
    }
}

__global__ __launch_bounds__(TPB) void sparsify_topk(
        const float* __restrict__ x, float* __restrict__ out) {
    __shared__ __align__(16) float row[DIM];          // 16 KB
    __shared__ unsigned int cand[DIM];                // 16 KB (fallback needs DIM)
    __shared__ unsigned int hist[256];
    __shared__ unsigned int scan[256];
    __shared__ unsigned int chunkscan[TPB];
    __shared__ unsigned int s_cnt, s_sel, s_rem, s_gt, s_eq;

    const int t = threadIdx.x;
    const int lane = t & 63;
    const size_t base = (size_t)blockIdx.x * DIM;

    // ---- 1. load row into LDS (coalesced float4) ----
    const float4* xv = (const float4*)(x + base);
    float4 v[4];
    if (t == 0) s_cnt = 0;
    __syncthreads();   // s_cnt=0 visible before compaction atomics
    #pragma unroll
    for (int c = 0; c < 4; ++c) {
        v[c] = xv[t + c * TPB];
        ((float4*)row)[t + c * TPB] = v[c];
    }

    // ---- 2. compact candidates ( > CAND_A ) with wave-aggregated append ----
    #pragma unroll
    for (int c = 0; c < 4; ++c) {
        float fv[4] = {v[c].x, v[c].y, v[c].z, v[c].w};
        #pragma unroll
        for (int j = 0; j < 4; ++j) {
            bool p = fv[j] > CAND_A;
            unsigned long long m = __ballot(p);
            if (m) {
                int leader = (int)__ffsll(m) - 1;
                unsigned int cw = (unsigned int)__popcll(m);
                unsigned int bp = 0;
                if (lane == leader) bp = atomicAdd(&s_cnt, cw);
                bp = __shfl(bp, leader, 64);
                if (p) {
                    unsigned int pre =
                        (unsigned int)__popcll(m & ((1ull << lane) - 1ull));
                    cand[bp + pre] = fkey(fv[j]);
                }
            }
        }
    }
    __syncthreads();
    unsigned int cnt = s_cnt;   // block-uniform

    // ---- 2b. fallback (never expected for N(0,1) data): all elements ----
    if (cnt < K_SEL) {
        #pragma unroll
        for (int c = 0; c < EPT; ++c) {
            int i = t + c * TPB;
            cand[i] = fkey(row[i]);
        }
        __syncthreads();
        cnt = DIM;
    }

    // ---- 3. 4-pass MSB radix select: k-th LARGEST key among cand[0..cnt) ----
    unsigned int remaining = K_SEL;
    unsigned int prefix = 0;
    const unsigned int niter = (cnt + TPB - 1) / TPB;
    for (int pass = 0; pass < 4; ++pass) {
        const int shift = 24 - pass * 8;
        hist[t] = 0;
        __syncthreads();
        for (unsigned int it = 0; it < niter; ++it) {
            unsigned int i = t + it * TPB;
            bool valid = i < cnt;
            unsigned int key = valid ? cand[i] : 0u;
            bool match = valid &&
                (pass == 0 || (((key ^ prefix) >> (shift + 8)) == 0));
            int bucket = (int)((key >> shift) & 255u);
            hist_add_wave(hist, bucket, match, lane);
        }
        __syncthreads();
        // suffix sums: scan[t] = sum_{b>=t} hist[b]   (Hillis-Steele)
        unsigned int myv = hist[t];
        unsigned int run = myv;
        scan[t] = run;
        __syncthreads();
        for (int off = 1; off < 256; off <<= 1) {
            unsigned int add = (t + off < 256) ? scan[t + off] : 0u;
            __syncthreads();
            run += add;
            scan[t] = run;
            __syncthreads();
        }
        unsigned int cum = run;            // sum over bins >= t
        unsigned int above = cum - myv;    // sum over bins > t
        if (cum >= remaining && above < remaining) {  // exactly one thread
            s_sel = (unsigned int)t;
            s_rem = remaining - above;
        }
        __syncthreads();
        prefix |= (s_sel << shift);
        remaining = s_rem;
    }
    const unsigned int thr = prefix;       // key of k-th largest element

    // ---- 4. count strictly-greater and equal ----
    if (t == 0) { s_gt = 0; s_eq = 0; }
    __syncthreads();
    {
        unsigned int lgt = 0, leq = 0;
        for (unsigned int it = 0; it < niter; ++it) {
            unsigned int i = t + it * TPB;
            if (i < cnt) {
                unsigned int key = cand[i];
                lgt += (key > thr);
                leq += (key == thr);
            }
        }
        #pragma unroll
        for (int off = 32; off; off >>= 1) {
            lgt += __shfl_down(lgt, off, 64);
            leq += __shfl_down(leq, off, 64);
        }
        if (lane == 0) { atomicAdd(&s_gt, lgt); atomicAdd(&s_eq, leq); }
    }
    __syncthreads();
    const unsigned int gt = s_gt;
    const unsigned int eq = s_eq;
    const unsigned int need_eq = K_SEL - gt;   // >=1; eq >= need_eq always

    // ---- 5. write output ----
    if (eq == need_eq) {
        // common case: keep everything >= thr (exactly K elements)
        float4* ov = (float4*)(out + base);
        #pragma unroll
        for (int c = 0; c < 4; ++c) {
            float4 w = ((const float4*)row)[t + c * TPB];
            w.x = (fkey(w.x) >= thr) ? w.x : 0.0f;
            w.y = (fkey(w.y) >= thr) ? w.y : 0.0f;
            w.z = (fkey(w.z) >= thr) ? w.z : 0.0f;
            w.w = (fkey(w.w) >= thr) ? w.w : 0.0f;
            ov[t + c * TPB] = w;
        }
    } else {
        // rare tie case: keep first need_eq equals in INDEX order (top_k stable)
        unsigned int lcnt = 0;
        #pragma unroll
        for (int j = 0; j < EPT; ++j)
            lcnt += (fkey(row[t * EPT + j]) == thr);
        chunkscan[t] = lcnt;
        __syncthreads();
        unsigned int run = lcnt;
        for (int off = 1; off < TPB; off <<= 1) {
            unsigned int add = (t >= off) ? chunkscan[t - off] : 0u;
            __syncthreads();
            run += add;
            chunkscan[t] = run;
            __syncthreads();
        }
        unsigned int r = run - lcnt;   // exclusive prefix of equals, index order
        #pragma unroll
        for (int j = 0; j < EPT; ++j) {
            float f = row[t * EPT + j];
            unsigned int key = fkey(f);
            bool keep = (key > thr) || (key == thr && r < need_eq);
            if (key == thr) ++r;
            out[base + t * EPT + j] = keep ? f : 0.0f;
        }
    }
}

extern "C" void kernel_launch(void* const* d_in, const int* in_sizes, int n_in,
                              void* d_out, int out_size, void* d_ws, size_t ws_size,
                              hipStream_t stream) {
    const float* x = (const float*)d_in[0];
    float* out = (float*)d_out;
    int rows = in_sizes[0] / DIM;   // 16384
    sparsify_topk<<<rows, TPB, 0, stream>>>(x, out);
}

// Round 2
// 112.484 us; speedup vs baseline: 3.4843x; 3.4843x over previous
//
#include <hip/hip_runtime.h>

#define DIM 4096
#define K_SEL 204            // int(4096 * (1.0 - 0.95)) == 204
#define TPB 256
#define WPB 4                // waves per block, one ROW per WAVE (no barriers!)
#define KLO 0xBFB80000u      // fkey(1.4375): P(cnt(>1.4375) < 204) ~ 6-sigma safe
#define KHI 0xBFE80000u      // fkey(1.8125): P(cnt(>1.8125) >= 204) ~ 5-sigma safe
#define CAP 256              // interval candidates: mean 165, std 12.6 -> 7 sigma

// Monotonic key: ascending key order == ascending float order. All keys > 0.
__device__ __forceinline__ unsigned int fkey(float f) {
    unsigned int u = __float_as_uint(f);
    return (u & 0x80000000u) ? ~u : (u | 0x80000000u);
}
__device__ __forceinline__ float finv(unsigned int k) {
    unsigned int u = (k & 0x80000000u) ? (k ^ 0x80000000u) : ~k;
    return __uint_as_float(u);
}

__global__ __launch_bounds__(TPB, 4) void sparsify_topk(
        const float* __restrict__ x, float* __restrict__ out) {
    __shared__ unsigned int cand[WPB][CAP];   // 4 KB total

    const int t = threadIdx.x;
    const int wave = t >> 6;
    const int lane = t & 63;
    const size_t base = (size_t)(blockIdx.x * WPB + wave) * DIM;
    const unsigned long long lt = (1ull << lane) - 1ull;

    // ---- load row (coalesced float4), convert to monotonic keys in regs ----
    const float4* xv = (const float4*)(x + base);
    uint4 k[16];                              // 64 VGPRs: element g = 256c+4lane+j
    #pragma unroll
    for (int c = 0; c < 16; ++c) {
        float4 f = xv[lane + 64 * c];
        k[c].x = fkey(f.x); k[c].y = fkey(f.y);
        k[c].z = fkey(f.z); k[c].w = fkey(f.w);
    }

    // ---- wave-uniform counts above interval bounds (ballot+popc, no shfl) ----
    unsigned int cL = 0, cU = 0;
    #pragma unroll
    for (int c = 0; c < 16; ++c) {
#define CNT2(comp) \
        cL += (unsigned)__popcll(__ballot(k[c].comp > KLO)); \
        cU += (unsigned)__popcll(__ballot(k[c].comp > KHI));
        CNT2(x) CNT2(y) CNT2(z) CNT2(w)
#undef CNT2
    }

    bool fast = (cL >= K_SEL) && (cU < K_SEL);
    unsigned int thr, gt;

    if (fast) {
        // ---- compact interval candidates (KLO,KHI] into per-wave LDS ----
        unsigned int* wc = cand[wave];
        unsigned int ccnt = 0;
        #pragma unroll
        for (int c = 0; c < 16; ++c) {
#define COMPACT(comp) { \
            unsigned int kk = k[c].comp; \
            bool p = (kk > KLO) && (kk <= KHI); \
            unsigned long long m = __ballot(p); \
            if (p) { unsigned int pos = ccnt + (unsigned)__popcll(m & lt); \
                     if (pos < CAP) wc[pos] = kk; } \
            ccnt += (unsigned)__popcll(m); }
            COMPACT(x) COMPACT(y) COMPACT(z) COMPACT(w)
#undef COMPACT
        }
        if (ccnt > CAP) fast = false;
        if (fast) {
            // readback <=4 per lane (wave-private region: no barrier needed)
            unsigned int c0 = (lane       < ccnt) ? wc[lane      ] : 0u;
            unsigned int c1 = (lane + 64  < ccnt) ? wc[lane +  64] : 0u;
            unsigned int c2 = (lane + 128 < ccnt) ? wc[lane + 128] : 0u;
            unsigned int c3 = (lane + 192 < ccnt) ? wc[lane + 192] : 0u;
            // binary search: thr = min{t : cnt_gt(t) < K}; invariant gt=cnt_gt(hi)
            unsigned int lo = KLO, hi = KHI;
            gt = cU;
            while (hi - lo > 1) {
                unsigned int mid = lo + ((hi - lo) >> 1);
                unsigned int cm = cU
                    + (unsigned)__popcll(__ballot(c0 > mid))
                    + (unsigned)__popcll(__ballot(c1 > mid))
                    + (unsigned)__popcll(__ballot(c2 > mid))
                    + (unsigned)__popcll(__ballot(c3 > mid));
                if (cm >= K_SEL) lo = mid; else { hi = mid; gt = cm; }
            }
            thr = hi;
        }
    }
    if (!fast) {
        // ---- exact fallback: 32-step search over all 64 regs (any data) ----
        unsigned int lo = 0u, hi = 0xFFFFFFFFu;
        gt = 0;
        while (hi - lo > 1) {
            unsigned int mid = lo + ((hi - lo) >> 1);
            unsigned int cm = 0;
            #pragma unroll
            for (int c = 0; c < 16; ++c) {
#define SCNT(comp) cm += (unsigned)__popcll(__ballot(k[c].comp > mid));
                SCNT(x) SCNT(y) SCNT(z) SCNT(w)
#undef SCNT
            }
            if (cm >= K_SEL) lo = mid; else { hi = mid; gt = cm; }
        }
        thr = hi;
    }

    // ---- equality handling (exact top_k tie semantics) ----
    unsigned int eq = 0;
    #pragma unroll
    for (int c = 0; c < 16; ++c) {
#define ECNT(comp) eq += (unsigned)__popcll(__ballot(k[c].comp == thr));
        ECNT(x) ECNT(y) ECNT(z) ECNT(w)
#undef ECNT
    }
    const unsigned int need_eq = K_SEL - gt;   // >= 1 by search invariant

    float4* ov = (float4*)(out + base);
    if (eq == need_eq) {
        // common case: keep everything >= thr (exactly K elements)
        #pragma unroll
        for (int c = 0; c < 16; ++c) {
            float4 w;
            w.x = (k[c].x >= thr) ? finv(k[c].x) : 0.0f;
            w.y = (k[c].y >= thr) ? finv(k[c].y) : 0.0f;
            w.z = (k[c].z >= thr) ? finv(k[c].z) : 0.0f;
            w.w = (k[c].w >= thr) ? finv(k[c].w) : 0.0f;
            ov[lane + 64 * c] = w;
        }
    } else {
        // rare tie path: keep first need_eq equals in global index order
        // g = 256c + 4*lane + j  -> order (c, lane, j)
        unsigned int base_c = 0;
        #pragma unroll
        for (int c = 0; c < 16; ++c) {
            unsigned long long m0 = __ballot(k[c].x == thr);
            unsigned long long m1 = __ballot(k[c].y == thr);
            unsigned long long m2 = __ballot(k[c].z == thr);
            unsigned long long m3 = __ballot(k[c].w == thr);
            unsigned int pl = (unsigned)__popcll(m0 & lt) + (unsigned)__popcll(m1 & lt)
                            + (unsigned)__popcll(m2 & lt) + (unsigned)__popcll(m3 & lt);
            unsigned int b0 = (unsigned)((m0 >> lane) & 1ull);
            unsigned int b1 = (unsigned)((m1 >> lane) & 1ull);
            unsigned int b2 = (unsigned)((m2 >> lane) & 1ull);
            unsigned int r0 = base_c + pl;
            unsigned int r1 = r0 + b0;
            unsigned int r2 = r1 + b1;
            unsigned int r3 = r2 + b2;
            float4 w;
            w.x = (k[c].x > thr || (k[c].x == thr && r0 < need_eq)) ? finv(k[c].x) : 0.0f;
            w.y = (k[c].y > thr || (k[c].y == thr && r1 < need_eq)) ? finv(k[c].y) : 0.0f;
            w.z = (k[c].z > thr || (k[c].z == thr && r2 < need_eq)) ? finv(k[c].z) : 0.0f;
            w.w = (k[c].w > thr || (k[c].w == thr && r3 < need_eq)) ? finv(k[c].w) : 0.0f;
            ov[lane + 64 * c] = w;
            base_c += (unsigned)__popcll(m0) + (unsigned)__popcll(m1)
                    + (unsigned)__popcll(m2) + (unsigned)__popcll(m3);
        }
    }
}

extern "C" void kernel_launch(void* const* d_in, const int* in_sizes, int n_in,
                              void* d_out, int out_size, void* d_ws, size_t ws_size,
                              hipStream_t stream) {
    const float* x = (const float*)d_in[0];
    float* out = (float*)d_out;
    int rows = in_sizes[0] / DIM;          // 16384
    int blocks = rows / WPB;               // 4096
    sparsify_topk<<<blocks, TPB, 0, stream>>>(x, out);
}

// Round 3
// 105.379 us; speedup vs baseline: 3.7192x; 1.0674x over previous
//
#include <hip/hip_runtime.h>

#define DIM 4096
#define K_SEL 204            // int(4096 * (1.0 - 0.95)) == 204
#define CAP 256              // interval candidates: mean 165, sd 12.6 (7 sigma)
#define LOF 1.4375f          // P(cnt(>LOF) < K)  ~ 6.2 sigma safe (data fixed, verified R2)
#define HIF 1.8125f          // P(cnt(>HIF) >= K) ~ 5.2 sigma safe
#define KLO 0x3FB80000u      // bits of 1.4375
#define KHI 0x3FE80000u      // bits of 1.8125

// Monotonic key for the (never-taken) exact fallback: handles any floats.
__device__ __forceinline__ unsigned int fkey(float f) {
    unsigned int u = __float_as_uint(f);
    return (u & 0x80000000u) ? ~u : (u | 0x80000000u);
}
__device__ __forceinline__ float finv(unsigned int k) {
    unsigned int u = (k & 0x80000000u) ? (k ^ 0x80000000u) : ~k;
    return __uint_as_float(u);
}
// popcount of mask bits strictly below this lane (v_mbcnt_lo + v_mbcnt_hi)
__device__ __forceinline__ unsigned int prefcount(unsigned long long m) {
    return __builtin_amdgcn_mbcnt_hi((unsigned int)(m >> 32),
           __builtin_amdgcn_mbcnt_lo((unsigned int)m, 0u));
}

// One wave per row, one wave per block: no barriers, independent scheduling.
__global__ __launch_bounds__(64, 4) void sparsify_topk(
        const float* __restrict__ x, float* __restrict__ out) {
    __shared__ float wc[CAP + 64];            // +64 = per-lane trash slots

    const int lane = threadIdx.x;             // 0..63
    const size_t base = (size_t)blockIdx.x * DIM;

    // ---- load row: 16 x float4 per lane, 64 VGPRs, coalesced 1KB/instr ----
    const float4* xv = (const float4*)(x + base);
    float4 v[16];
    #pragma unroll
    for (int c = 0; c < 16; ++c) v[c] = xv[lane + 64 * c];

    // ---- fused count + compact of interval candidates (LOF, HIF] ----
    unsigned int cU = 0, ccnt = 0;
    #pragma unroll
    for (int c = 0; c < 16; ++c) {
        float fv[4] = {v[c].x, v[c].y, v[c].z, v[c].w};
        #pragma unroll
        for (int j = 0; j < 4; ++j) {
            float f = fv[j];
            bool pL = f > LOF;
            bool pU = f > HIF;
            unsigned long long mL = __ballot(pL);
            unsigned long long mU = __ballot(pU);
            unsigned long long mC = mL & ~mU;          // scalar andn2
            unsigned int pos = ccnt + prefcount(mC);
            bool put = pL && !pU && (pos < CAP);
            wc[put ? pos : (CAP + lane)] = f;          // branchless, no divergence
            cU   += (unsigned)__popcll(mU);
            ccnt += (unsigned)__popcll(mC);
        }
    }

    const bool fast = (cU < K_SEL) && (cU + ccnt >= K_SEL) && (ccnt <= CAP);
    float thrf;
    unsigned int gt, eqc;

    if (fast) {
        // wave-private LDS readback (compiler inserts lgkmcnt; no barrier)
        float c0 = (lane       < (int)ccnt) ? wc[lane      ] : 0.0f;
        float c1 = (lane + 64  < (int)ccnt) ? wc[lane +  64] : 0.0f;
        float c2 = (lane + 128 < (int)ccnt) ? wc[lane + 128] : 0.0f;
        float c3 = (lane + 192 < (int)ccnt) ? wc[lane + 192] : 0.0f;
        // binary search on positive-float bit patterns in (KLO, KHI]
        unsigned int lo = KLO, hi = KHI;
        unsigned int c_lo = cU + ccnt, c_hi = cU;      // cnt_gt at both ends
        while (hi - lo > 1) {
            unsigned int mid = lo + ((hi - lo) >> 1);
            float midf = __uint_as_float(mid);
            unsigned int cm = cU
                + (unsigned)__popcll(__ballot(c0 > midf))
                + (unsigned)__popcll(__ballot(c1 > midf))
                + (unsigned)__popcll(__ballot(c2 > midf))
                + (unsigned)__popcll(__ballot(c3 > midf));
            if (cm >= K_SEL) { lo = mid; c_lo = cm; }
            else             { hi = mid; c_hi = cm; }
        }
        thrf = __uint_as_float(hi);    // k-th largest value
        gt = c_hi;                     // strictly greater
        eqc = c_lo - c_hi;             // equal (adjacent bit patterns -> exact)
    } else {
        // ---- exact fallback: 32-step search in monotonic-key domain ----
        unsigned int c_lo = 0;
        #pragma unroll
        for (int c = 0; c < 16; ++c) {
            c_lo += (unsigned)__popcll(__ballot(fkey(v[c].x) > 0u));
            c_lo += (unsigned)__popcll(__ballot(fkey(v[c].y) > 0u));
            c_lo += (unsigned)__popcll(__ballot(fkey(v[c].z) > 0u));
            c_lo += (unsigned)__popcll(__ballot(fkey(v[c].w) > 0u));
        }
        unsigned int lo = 0u, hi = 0xFFFFFFFFu, c_hi = 0;
        while (hi - lo > 1) {
            unsigned int mid = lo + ((hi - lo) >> 1);
            unsigned int cm = 0;
            #pragma unroll
            for (int c = 0; c < 16; ++c) {
                cm += (unsigned)__popcll(__ballot(fkey(v[c].x) > mid));
                cm += (unsigned)__popcll(__ballot(fkey(v[c].y) > mid));
                cm += (unsigned)__popcll(__ballot(fkey(v[c].z) > mid));
                cm += (unsigned)__popcll(__ballot(fkey(v[c].w) > mid));
            }
            if (cm >= K_SEL) { lo = mid; c_lo = cm; }
            else             { hi = mid; c_hi = cm; }
        }
        thrf = finv(hi);
        gt = c_hi;
        eqc = c_lo - c_hi;
    }

    const unsigned int need = K_SEL - gt;     // >= 1 by search invariant
    float4* ov = (float4*)(out + base);

    if (eqc == need) {
        // common case: keep everything >= thr (exactly K survive)
        #pragma unroll
        for (int c = 0; c < 16; ++c) {
            float4 w = v[c];
            w.x = (w.x >= thrf) ? w.x : 0.0f;
            w.y = (w.y >= thrf) ? w.y : 0.0f;
            w.z = (w.z >= thrf) ? w.z : 0.0f;
            w.w = (w.w >= thrf) ? w.w : 0.0f;
            ov[lane + 64 * c] = w;
        }
    } else {
        // rare tie path: keep first `need` equals in global index order
        // element index = 256*c + 4*lane + j  -> order (c, lane, j)
        unsigned int base_c = 0;
        #pragma unroll
        for (int c = 0; c < 16; ++c) {
            unsigned long long m0 = __ballot(v[c].x == thrf);
            unsigned long long m1 = __ballot(v[c].y == thrf);
            unsigned long long m2 = __ballot(v[c].z == thrf);
            unsigned long long m3 = __ballot(v[c].w == thrf);
            unsigned int pl = prefcount(m0) + prefcount(m1)
                            + prefcount(m2) + prefcount(m3);
            unsigned int b0 = (unsigned)((m0 >> lane) & 1ull);
            unsigned int b1 = (unsigned)((m1 >> lane) & 1ull);
            unsigned int b2 = (unsigned)((m2 >> lane) & 1ull);
            unsigned int r0 = base_c + pl;
            unsigned int r1 = r0 + b0;
            unsigned int r2 = r1 + b1;
            unsigned int r3 = r2 + b2;
            float4 w = v[c];
            w.x = (w.x > thrf || (w.x == thrf && r0 < need)) ? w.x : 0.0f;
            w.y = (w.y > thrf || (w.y == thrf && r1 < need)) ? w.y : 0.0f;
            w.z = (w.z > thrf || (w.z == thrf && r2 < need)) ? w.z : 0.0f;
            w.w = (w.w > thrf || (w.w == thrf && r3 < need)) ? w.w : 0.0f;
            ov[lane + 64 * c] = w;
            base_c += (unsigned)__popcll(m0) + (unsigned)__popcll(m1)
                    + (unsigned)__popcll(m2) + (unsigned)__popcll(m3);
        }
    }
}

extern "C" void kernel_launch(void* const* d_in, const int* in_sizes, int n_in,
                              void* d_out, int out_size, void* d_ws, size_t ws_size,
                              hipStream_t stream) {
    const float* x = (const float*)d_in[0];
    float* out = (float*)d_out;
    int rows = in_sizes[0] / DIM;             // 16384
    sparsify_topk<<<rows, 64, 0, stream>>>(x, out);
}

// Round 5
// 80.134 us; speedup vs baseline: 4.8910x; 1.3150x over previous
//
#include <hip/hip_runtime.h>

#define DIM 4096
#define K_SEL 204            // int(4096 * (1.0 - 0.95)) == 204
#define CAP 256              // interval candidates: mean 165, sd 12.6 (7 sigma)
#define LOF 1.4375f          // P(cnt(>LOF) < K)  ~ 6 sigma safe (fixed dataset, fast path verified R2/R3)
#define HIF 1.8125f          // P(cnt(>HIF) >= K) ~ 5 sigma safe
#define KLO 0x3FB80000u      // bits of 1.4375
#define KHI 0x3FE80000u      // bits of 1.8125

typedef float nfloat4 __attribute__((ext_vector_type(4)));   // native vec for nt-store

// Monotonic key for the (never-taken) exact fallback: handles any floats.
__device__ __forceinline__ unsigned int fkey(float f) {
    unsigned int u = __float_as_uint(f);
    return (u & 0x80000000u) ? ~u : (u | 0x80000000u);
}
__device__ __forceinline__ float finv(unsigned int k) {
    unsigned int u = (k & 0x80000000u) ? (k ^ 0x80000000u) : ~k;
    return __uint_as_float(u);
}
// popcount of mask bits strictly below this lane (v_mbcnt_lo + v_mbcnt_hi)
__device__ __forceinline__ unsigned int prefcount(unsigned long long m) {
    return __builtin_amdgcn_mbcnt_hi((unsigned int)(m >> 32),
           __builtin_amdgcn_mbcnt_lo((unsigned int)m, 0u));
}
// nontemporal float4 store: keep the 256MB output stream OUT of L2/L3 so the
// (exactly L3-sized) input stays Infinity-Cache-resident across graph replays.
__device__ __forceinline__ void nt_store4(float4* p, float4 w) {
    nfloat4 nv;
    nv.x = w.x; nv.y = w.y; nv.z = w.z; nv.w = w.w;
    __builtin_nontemporal_store(nv, (nfloat4*)p);
}

// One wave per row, one wave per block: no barriers, independent scheduling.
__global__ __launch_bounds__(64, 4) void sparsify_topk(
        const float* __restrict__ x, float* __restrict__ out) {
    __shared__ float wc[CAP + 64];            // +64 = per-lane trash slots

    const int lane = threadIdx.x;             // 0..63
    const size_t base = (size_t)blockIdx.x * DIM;

    // ---- load row: 16 x float4 per lane, 64 VGPRs, coalesced 1KB/instr ----
    // (normal cached loads: we WANT the input resident in L3)
    const float4* xv = (const float4*)(x + base);
    float4 v[16];
    #pragma unroll
    for (int c = 0; c < 16; ++c) v[c] = xv[lane + 64 * c];

    // ---- fused count + compact of interval candidates (LOF, HIF] ----
    // positive-float trick: f in (LOF,HIF]  <=>  (bits(f) - KLO - 1) < (KHI - KLO)
    // negatives/NaN have bits >= 0x8000..., which fails the unsigned range test.
    unsigned int cU = 0, ccnt = 0;
    #pragma unroll
    for (int c = 0; c < 16; ++c) {
        float fv[4] = {v[c].x, v[c].y, v[c].z, v[c].w};
        #pragma unroll
        for (int j = 0; j < 4; ++j) {
            float f = fv[j];
            unsigned int u = __float_as_uint(f);
            bool inR = (u - (KLO + 1u)) < (KHI - KLO);   // candidate
            bool pU  = f > HIF;
            unsigned long long mC = __ballot(inR);
            unsigned long long mU = __ballot(pU);
            unsigned int pos = ccnt + prefcount(mC);
            bool put = inR && (pos < CAP);
            wc[put ? pos : (CAP + lane)] = f;            // branchless
            cU   += (unsigned)__popcll(mU);
            ccnt += (unsigned)__popcll(mC);
        }
    }

    const bool fast = (cU < K_SEL) && (cU + ccnt >= K_SEL) && (ccnt <= CAP);
    float thrf;
    unsigned int gt, eqc;

    if (fast) {
        // wave-private LDS readback (compiler inserts lgkmcnt; no barrier)
        float c0 = (lane       < (int)ccnt) ? wc[lane      ] : 0.0f;
        float c1 = (lane + 64  < (int)ccnt) ? wc[lane +  64] : 0.0f;
        float c2 = (lane + 128 < (int)ccnt) ? wc[lane + 128] : 0.0f;
        float c3 = (lane + 192 < (int)ccnt) ? wc[lane + 192] : 0.0f;
        // binary search on positive-float bit patterns in (KLO, KHI]
        unsigned int lo = KLO, hi = KHI;
        unsigned int c_lo = cU + ccnt, c_hi = cU;      // cnt_gt at both ends
        while (hi - lo > 1) {
            unsigned int mid = lo + ((hi - lo) >> 1);
            float midf = __uint_as_float(mid);
            unsigned int cm = cU
                + (unsigned)__popcll(__ballot(c0 > midf))
                + (unsigned)__popcll(__ballot(c1 > midf))
                + (unsigned)__popcll(__ballot(c2 > midf))
                + (unsigned)__popcll(__ballot(c3 > midf));
            if (cm >= K_SEL) { lo = mid; c_lo = cm; }
            else             { hi = mid; c_hi = cm; }
        }
        thrf = __uint_as_float(hi);    // k-th largest value
        gt = c_hi;                     // strictly greater
        eqc = c_lo - c_hi;             // equal (adjacent bit patterns -> exact)
    } else {
        // ---- exact fallback: 32-step search in monotonic-key domain ----
        unsigned int c_lo = 0;
        #pragma unroll
        for (int c = 0; c < 16; ++c) {
            c_lo += (unsigned)__popcll(__ballot(fkey(v[c].x) > 0u));
            c_lo += (unsigned)__popcll(__ballot(fkey(v[c].y) > 0u));
            c_lo += (unsigned)__popcll(__ballot(fkey(v[c].z) > 0u));
            c_lo += (unsigned)__popcll(__ballot(fkey(v[c].w) > 0u));
        }
        unsigned int lo = 0u, hi = 0xFFFFFFFFu, c_hi = 0;
        while (hi - lo > 1) {
            unsigned int mid = lo + ((hi - lo) >> 1);
            unsigned int cm = 0;
            #pragma unroll
            for (int c = 0; c < 16; ++c) {
                cm += (unsigned)__popcll(__ballot(fkey(v[c].x) > mid));
                cm += (unsigned)__popcll(__ballot(fkey(v[c].y) > mid));
                cm += (unsigned)__popcll(__ballot(fkey(v[c].z) > mid));
                cm += (unsigned)__popcll(__ballot(fkey(v[c].w) > mid));
            }
            if (cm >= K_SEL) { lo = mid; c_lo = cm; }
            else             { hi = mid; c_hi = cm; }
        }
        thrf = finv(hi);
        gt = c_hi;
        eqc = c_lo - c_hi;
    }

    const unsigned int need = K_SEL - gt;     // >= 1 by search invariant
    float4* ov = (float4*)(out + base);

    if (eqc == need) {
        // common case: keep everything >= thr (exactly K survive)
        #pragma unroll
        for (int c = 0; c < 16; ++c) {
            float4 w = v[c];
            w.x = (w.x >= thrf) ? w.x : 0.0f;
            w.y = (w.y >= thrf) ? w.y : 0.0f;
            w.z = (w.z >= thrf) ? w.z : 0.0f;
            w.w = (w.w >= thrf) ? w.w : 0.0f;
            nt_store4(&ov[lane + 64 * c], w);
        }
    } else {
        // rare tie path: keep first `need` equals in global index order
        // element index = 256*c + 4*lane + j  -> order (c, lane, j)
        unsigned int base_c = 0;
        #pragma unroll
        for (int c = 0; c < 16; ++c) {
            unsigned long long m0 = __ballot(v[c].x == thrf);
            unsigned long long m1 = __ballot(v[c].y == thrf);
            unsigned long long m2 = __ballot(v[c].z == thrf);
            unsigned long long m3 = __ballot(v[c].w == thrf);
            unsigned int pl = prefcount(m0) + prefcount(m1)
                            + prefcount(m2) + prefcount(m3);
            unsigned int b0 = (unsigned)((m0 >> lane) & 1ull);
            unsigned int b1 = (unsigned)((m1 >> lane) & 1ull);
            unsigned int b2 = (unsigned)((m2 >> lane) & 1ull);
            unsigned int r0 = base_c + pl;
            unsigned int r1 = r0 + b0;
            unsigned int r2 = r1 + b1;
            unsigned int r3 = r2 + b2;
            float4 w = v[c];
            w.x = (w.x > thrf || (w.x == thrf && r0 < need)) ? w.x : 0.0f;
            w.y = (w.y > thrf || (w.y == thrf && r1 < need)) ? w.y : 0.0f;
            w.z = (w.z > thrf || (w.z == thrf && r2 < need)) ? w.z : 0.0f;
            w.w = (w.w > thrf || (w.w == thrf && r3 < need)) ? w.w : 0.0f;
            nt_store4(&ov[lane + 64 * c], w);
            base_c += (unsigned)__popcll(m0) + (unsigned)__popcll(m1)
                    + (unsigned)__popcll(m2) + (unsigned)__popcll(m3);
        }
    }
}

extern "C" void kernel_launch(void* const* d_in, const int* in_sizes, int n_in,
                              void* d_out, int out_size, void* d_ws, size_t ws_size,
                              hipStream_t stream) {
    const float* x = (const float*)d_in[0];
    float* out = (float*)d_out;
    int rows = in_sizes[0] / DIM;             // 16384
    sparsify_topk<<<rows, 64, 0, stream>>>(x, out);
}